// Round 1
// baseline (168.830 us; speedup 1.0000x reference)
//
#include <hip/hip_runtime.h>
#include <math.h>

// Problem constants (fixed by setup_inputs): B=4, N=M=P=2048, NS=1024.
// out = [4,2048,2048] fp32, out_size = 16777216.
// Scratch: per-point min-d2 arrays live in the TAIL of d_out (overwritten by
// the final kernel, which runs last and never reads them). Layout (floats):
//   [0)      8192  cd dir2: min over pc2 for each pc1_0 point (flattened)
//   [8192)   8192  cd dir1: min over pc1_0 for each pc2 point
//   [16384)  4096  seed dir2: min over pc2 for each pc1_1 point
//   [20480)  8192  seed dir1: min over pc1_1 for each pc2 point
//   [28672)  8192  conf: min over pc2[b] for each pc3[b,p]  (batched)
// ws[0] holds the scalar S = conf_loss + 0.5*cd + seed_loss.

constexpr int GMIN_TOTAL = 36864;                  // 8192*4 + 4096
constexpr int OUT_TOTAL  = 4 * 2048 * 2048;
constexpr int GMIN_OFS   = OUT_TOTAL - GMIN_TOTAL; // tail of d_out

__global__ __launch_bounds__(256) void init_min(unsigned int* __restrict__ g) {
    int i = blockIdx.x * 256 + threadIdx.x;   // grid = 144 blocks -> exactly 36864
    g[i] = 0x7F800000u;                       // +inf
}

// Fused NN-min kernel. Each block: 1024 a-points (4/thread) x 512 b-points
// (staged in LDS). Job decoded from blockIdx.x with compile-time geometry:
//   [0,128)   cd:   A=pc1_0(8192) vs B=pc2(8192)   -> gofs 0
//   [128,256) cd:   A=pc2(8192)   vs B=pc1_0(8192) -> gofs 8192
//   [256,320) seed: A=pc1_1(4096) vs B=pc2(8192)   -> gofs 16384
//   [320,384) seed: A=pc2(8192)   vs B=pc1_1(4096) -> gofs 20480
//   [384,416) conf: A=pc3[b](2048) vs B=pc2[b](2048), b=(bid-384)/8 -> 28672+b*2048
__global__ __launch_bounds__(256) void nn_kernel(
    const float* __restrict__ A0,   // pc1_0 flat (8192 pts)
    const float* __restrict__ A1,   // pc1_1 flat (4096 pts)
    const float* __restrict__ P2,   // pc2   flat (8192 pts / 4 batches x 2048)
    const float* __restrict__ P3,   // pc3   (4 x 2048 pts)
    float* __restrict__ gmin)
{
    __shared__ float lds[1536];     // 512 b-points x 3
    int bid = blockIdx.x;
    const float* A; const float* Bp; int b_tiles; int gofs; int local;
    if (bid < 128)      { local = bid;       A = A0; Bp = P2; b_tiles = 16; gofs = 0; }
    else if (bid < 256) { local = bid - 128; A = P2; Bp = A0; b_tiles = 16; gofs = 8192; }
    else if (bid < 320) { local = bid - 256; A = A1; Bp = P2; b_tiles = 16; gofs = 16384; }
    else if (bid < 384) { local = bid - 320; A = P2; Bp = A1; b_tiles = 8;  gofs = 20480; }
    else { int l2 = bid - 384; int bt = l2 >> 3; local = l2 & 7;
           A = P3 + bt * 6144; Bp = P2 + bt * 6144; b_tiles = 4; gofs = 28672 + bt * 2048; }
    int a_tile = local / b_tiles;
    int b_tile = local - a_tile * b_tiles;

    // stage 512 b-points (coalesced)
    const float* bsrc = Bp + b_tile * 1536;
    for (int i = threadIdx.x; i < 1536; i += 256) lds[i] = bsrc[i];

    // 4 a-points per thread (12 consecutive floats, 16B-aligned -> 3x float4)
    int a_base = a_tile * 1024 + threadIdx.x * 4;
    const float4* av = (const float4*)(A + a_base * 3);
    float4 v0 = av[0], v1 = av[1], v2 = av[2];
    float ax[4], ay[4], az[4], a2[4], mn[4];
    ax[0]=v0.x; ay[0]=v0.y; az[0]=v0.z;
    ax[1]=v0.w; ay[1]=v1.x; az[1]=v1.y;
    ax[2]=v1.z; ay[2]=v1.w; az[2]=v2.x;
    ax[3]=v2.y; ay[3]=v2.z; az[3]=v2.w;
    #pragma unroll
    for (int k = 0; k < 4; k++) {
        a2[k] = fmaf(ax[k], ax[k], fmaf(ay[k], ay[k], az[k]*az[k]));
        mn[k] = 3.4e38f;
    }
    __syncthreads();

    // min over b of (|b|^2 - 2 a.b); add |a|^2 at the end (monotone-equivalent)
    #pragma unroll 4
    for (int j = 0; j < 512; j++) {
        float bx = lds[3*j], by = lds[3*j+1], bz = lds[3*j+2];
        float b2 = fmaf(bx, bx, fmaf(by, by, bz*bz));
        #pragma unroll
        for (int k = 0; k < 4; k++) {
            float t = fmaf(ax[k], bx, fmaf(ay[k], by, az[k]*bz));
            mn[k] = fminf(mn[k], fmaf(-2.f, t, b2));
        }
    }
    #pragma unroll
    for (int k = 0; k < 4; k++) {
        float d2 = fmaxf(a2[k] + mn[k], 0.f);  // clip like the reference
        // nonneg float: uint compare == float compare
        atomicMin((unsigned int*)(gmin + gofs + a_base + k), __float_as_uint(d2));
    }
}

__global__ __launch_bounds__(256) void reduce_kernel(
    const float* __restrict__ gmin,
    const float* __restrict__ conf_in,   // pc1_3, 8192 values
    float* __restrict__ S_out)
{
    int tid = threadIdx.x;
    float s[5] = {0.f, 0.f, 0.f, 0.f, 0.f};
    for (int i = tid; i < 8192; i += 256) s[0] += sqrtf(gmin[i]);
    for (int i = tid; i < 8192; i += 256) s[1] += sqrtf(gmin[8192 + i]);
    for (int i = tid; i < 4096; i += 256) s[2] += sqrtf(gmin[16384 + i]);
    for (int i = tid; i < 8192; i += 256) s[3] += sqrtf(gmin[20480 + i]);
    for (int i = tid; i < 8192; i += 256) {
        float d = sqrtf(gmin[28672 + i]);
        float e = conf_in[i] - __expf(-d);
        s[4] += e * e;
    }
    __shared__ float red[256];
    float tot[5];
    for (int v = 0; v < 5; v++) {
        red[tid] = s[v]; __syncthreads();
        for (int ofs = 128; ofs > 0; ofs >>= 1) {
            if (tid < ofs) red[tid] += red[tid + ofs];
            __syncthreads();
        }
        tot[v] = red[0]; __syncthreads();
    }
    if (tid == 0) {
        float cd   = tot[0] * (1.f/8192.f) + tot[1] * (1.f/8192.f);
        float seed = tot[2] * (1.f/4096.f) + tot[3] * (1.f/8192.f);
        float conf = tot[4] * (1.f/8192.f);
        S_out[0] = conf + 0.5f * cd + seed;
    }
}

// out[b,n,m] = S + 0.5 * dist(pc1_0[b,n], pc2[b,m]).
// Block = (batch, group of 8 n-rows). Thread owns m = tid*4..+3 and
// 1024+tid*4..+3 (8 pc2 points in registers), float4 stores -> write-bound.
__global__ __launch_bounds__(256) void out_kernel(
    const float* __restrict__ pc1_0,
    const float* __restrict__ pc2,
    const float* __restrict__ Sp,
    float* __restrict__ out)
{
    int blk = blockIdx.x;            // 1024 blocks
    int batch = blk >> 8;
    int n8 = blk & 255;
    int tid = threadIdx.x;
    float S = Sp[0];
    const float* bb = pc2 + batch * 6144;
    float bx[8], by[8], bz[8];
    {
        const float4* p = (const float4*)(bb + tid * 12);
        float4 u0 = p[0], u1 = p[1], u2 = p[2];
        bx[0]=u0.x; by[0]=u0.y; bz[0]=u0.z;
        bx[1]=u0.w; by[1]=u1.x; bz[1]=u1.y;
        bx[2]=u1.z; by[2]=u1.w; bz[2]=u2.x;
        bx[3]=u2.y; by[3]=u2.z; bz[3]=u2.w;
    }
    {
        const float4* p = (const float4*)(bb + 3072 + tid * 12);
        float4 u0 = p[0], u1 = p[1], u2 = p[2];
        bx[4]=u0.x; by[4]=u0.y; bz[4]=u0.z;
        bx[5]=u0.w; by[5]=u1.x; bz[5]=u1.y;
        bx[6]=u1.z; by[6]=u1.w; bz[6]=u2.x;
        bx[7]=u2.y; by[7]=u2.z; bz[7]=u2.w;
    }
    const float* arow = pc1_0 + batch * 6144 + n8 * 24;  // 8 rows x 3 (uniform)
    float* ob = out + (long)((batch << 11) + (n8 << 3)) * 2048 + tid * 4;
    #pragma unroll
    for (int r = 0; r < 8; r++) {
        float axx = arow[r*3], ayy = arow[r*3+1], azz = arow[r*3+2];
        float o[8];
        #pragma unroll
        for (int k = 0; k < 8; k++) {
            float dx = axx - bx[k], dy = ayy - by[k], dz = azz - bz[k];
            float d2 = fmaf(dx, dx, fmaf(dy, dy, dz*dz));
            o[k] = fmaf(0.5f, sqrtf(d2), S);
        }
        *(float4*)(ob + r * 2048)        = make_float4(o[0], o[1], o[2], o[3]);
        *(float4*)(ob + r * 2048 + 1024) = make_float4(o[4], o[5], o[6], o[7]);
    }
}

extern "C" void kernel_launch(void* const* d_in, const int* in_sizes, int n_in,
                              void* d_out, int out_size, void* d_ws, size_t ws_size,
                              hipStream_t stream) {
    const float* pc1_0 = (const float*)d_in[0];  // [4,2048,3]
    const float* pc1_1 = (const float*)d_in[1];  // [4,1024,3]
    const float* pc1_3 = (const float*)d_in[2];  // [4,2048,1]
    const float* pc2   = (const float*)d_in[3];  // [4,2048,3]
    const float* pc3   = (const float*)d_in[4];  // [4,2048,3]
    float* out = (float*)d_out;
    float* ws  = (float*)d_ws;                   // ws[0] = scalar S
    float* gmin = out + GMIN_OFS;                // scratch in d_out tail

    init_min<<<GMIN_TOTAL / 256, 256, 0, stream>>>((unsigned int*)gmin);
    nn_kernel<<<416, 256, 0, stream>>>(pc1_0, pc1_1, pc2, pc3, gmin);
    reduce_kernel<<<1, 256, 0, stream>>>(gmin, pc1_3, ws);
    out_kernel<<<1024, 256, 0, stream>>>(pc1_0, pc2, ws, out);
}

// Round 2
// 114.383 us; speedup vs baseline: 1.4760x; 1.4760x over previous
//
#include <hip/hip_runtime.h>
#include <math.h>

// Problem constants (fixed by setup_inputs): B=4, N=M=P=2048, NS=1024.
// out = [4,2048,2048] fp32, out_size = 16777216.
// Scratch: per-point min-d2' arrays live in the TAIL of d_out (overwritten by
// the final kernel, which runs last and never reads them). Layout (floats):
//   [0)      8192  cd dir2: min over pc2 for each pc1_0 point (flattened)
//   [8192)   8192  cd dir1: min over pc1_0 for each pc2 point
//   [16384)  4096  seed dir2: min over pc2 for each pc1_1 point
//   [20480)  8192  seed dir1: min over pc1_1 for each pc2 point
//   [28672)  8192  conf: min over pc2[b] for each pc3[b,p]  (batched)
// Values stored are d2 = max(|a|^2 + 2*min_b(|b|^2/2 - a.b), 0)  (exact d2).
// ws[1] accumulates the scalar S = conf_mse + 0.5*cd + seed_loss (pre-scaled
// atomicAdd partials from 36 reduce blocks).

constexpr int GMIN_TOTAL = 36864;                  // 8192*4 + 4096
constexpr int OUT_TOTAL  = 4 * 2048 * 2048;
constexpr int GMIN_OFS   = OUT_TOTAL - GMIN_TOTAL; // tail of d_out

__global__ __launch_bounds__(256) void init_min(unsigned int* __restrict__ g,
                                                float* __restrict__ ws) {
    int blk = blockIdx.x;                     // 145 blocks
    if (blk == 144) { if (threadIdx.x < 8) ws[threadIdx.x] = 0.f; return; }
    int i = blk * 256 + threadIdx.x;          // exactly 36864
    g[i] = 0x7F800000u;                       // +inf
}

// Fused NN-min kernel. Each block: 1024 a-points (4/thread) x 256 b-points
// (LDS float4: x,y,z,half|b|^2). Job decoded from blockIdx.x (832 blocks):
//   [0,256)    cd:   A=pc1_0(8192) vs B=pc2(8192)   gofs 0      (8 at x 32 bt)
//   [256,512)  cd:   A=pc2(8192)   vs B=pc1_0(8192) gofs 8192   (8 at x 32 bt)
//   [512,640)  seed: A=pc1_1(4096) vs B=pc2(8192)   gofs 16384  (4 at x 32 bt)
//   [640,768)  seed: A=pc2(8192)   vs B=pc1_1(4096) gofs 20480  (8 at x 16 bt)
//   [768,832)  conf: A=pc3[b](2048) vs B=pc2[b](2048), 16 blocks/batch
__global__ __launch_bounds__(256) void nn_kernel(
    const float* __restrict__ A0,   // pc1_0 flat (8192 pts)
    const float* __restrict__ A1,   // pc1_1 flat (4096 pts)
    const float* __restrict__ P2,   // pc2   flat (8192 pts / 4 batches x 2048)
    const float* __restrict__ P3,   // pc3   (4 x 2048 pts)
    float* __restrict__ gmin)
{
    __shared__ float4 lds[256];
    int bid = blockIdx.x;
    const float* A; const float* Bp; int b_tiles; int gofs; int local;
    if (bid < 256)      { local = bid;       A = A0; Bp = P2; b_tiles = 32; gofs = 0; }
    else if (bid < 512) { local = bid - 256; A = P2; Bp = A0; b_tiles = 32; gofs = 8192; }
    else if (bid < 640) { local = bid - 512; A = A1; Bp = P2; b_tiles = 32; gofs = 16384; }
    else if (bid < 768) { local = bid - 640; A = P2; Bp = A1; b_tiles = 16; gofs = 20480; }
    else { int l2 = bid - 768; int bt = l2 >> 4; local = l2 & 15;
           A = P3 + bt * 6144; Bp = P2 + bt * 6144; b_tiles = 8; gofs = 28672 + bt * 2048; }
    int a_tile = local / b_tiles;
    int b_tile = local - a_tile * b_tiles;

    // stage 256 b-points: (x, y, z, 0.5*|b|^2) per point
    {
        const float* s = Bp + (b_tile * 256 + threadIdx.x) * 3;
        float bx = s[0], by = s[1], bz = s[2];
        float hb2 = 0.5f * fmaf(bx, bx, fmaf(by, by, bz * bz));
        lds[threadIdx.x] = make_float4(bx, by, bz, hb2);
    }

    // 4 a-points per thread (12 consecutive floats, 16B-aligned -> 3x float4)
    int a_base = a_tile * 1024 + threadIdx.x * 4;
    const float4* av = (const float4*)(A + a_base * 3);
    float4 v0 = av[0], v1 = av[1], v2 = av[2];
    float ax[4], ay[4], az[4], a2[4], mn[4];
    ax[0]=v0.x; ay[0]=v0.y; az[0]=v0.z;
    ax[1]=v0.w; ay[1]=v1.x; az[1]=v1.y;
    ax[2]=v1.z; ay[2]=v1.w; az[2]=v2.x;
    ax[3]=v2.y; ay[3]=v2.z; az[3]=v2.w;
    #pragma unroll
    for (int k = 0; k < 4; k++) {
        a2[k] = fmaf(ax[k], ax[k], fmaf(ay[k], ay[k], az[k]*az[k]));
        mn[k] = 3.4e38f;
    }
    __syncthreads();

    // min over b of (|b|^2/2 - a.b); d2 = |a|^2 + 2*mn (monotone-equivalent)
    #pragma unroll 4
    for (int j = 0; j < 256; j++) {
        float4 b = lds[j];
        #pragma unroll
        for (int k = 0; k < 4; k++) {
            float t = fmaf(ax[k], b.x, fmaf(ay[k], b.y, az[k]*b.z));
            mn[k] = fminf(mn[k], b.w - t);
        }
    }
    #pragma unroll
    for (int k = 0; k < 4; k++) {
        float d2 = fmaxf(fmaf(2.f, mn[k], a2[k]), 0.f);  // clip like reference
        // nonneg float: uint compare == float compare
        atomicMin((unsigned int*)(gmin + gofs + a_base + k), __float_as_uint(d2));
    }
}

// 36 blocks x 1024 elements. Each block sums its slice (sqrt / conf-MSE),
// scales by the linear weight of its loss term, and atomicAdds into ws[1].
__global__ __launch_bounds__(256) void reduce_kernel(
    const float* __restrict__ gmin,
    const float* __restrict__ conf_in,   // pc1_3, 8192 values
    float* __restrict__ ws)
{
    int blk = blockIdx.x;
    int tid = threadIdx.x;
    int base = blk * 1024;
    float sum = 0.f;
    if (blk < 28) {
        #pragma unroll
        for (int r = 0; r < 4; r++) sum += sqrtf(gmin[base + tid + r * 256]);
    } else {
        int cbase = base - 28672;
        #pragma unroll
        for (int r = 0; r < 4; r++) {
            int i = tid + r * 256;
            float d = sqrtf(gmin[base + i]);
            float e = conf_in[cbase + i] - __expf(-d);
            sum += e * e;
        }
    }
    // wave reduce (64 lanes)
    #pragma unroll
    for (int ofs = 32; ofs > 0; ofs >>= 1) sum += __shfl_down(sum, ofs);
    __shared__ float red[4];
    int wave = tid >> 6;
    if ((tid & 63) == 0) red[wave] = sum;
    __syncthreads();
    if (tid == 0) {
        float tot = red[0] + red[1] + red[2] + red[3];
        float scale = (blk < 16) ? 0.5f / 8192.f
                    : (blk < 20) ? 1.f / 4096.f
                    :              1.f / 8192.f;
        atomicAdd(&ws[1], tot * scale);
    }
}

// out[b,n,m] = S + 0.5 * dist(pc1_0[b,n], pc2[b,m]).
// Block = (batch, group of 8 n-rows). Thread owns m = tid*4..+3 and
// 1024+tid*4..+3 (8 pc2 points in registers), float4 stores -> write-bound.
__global__ __launch_bounds__(256) void out_kernel(
    const float* __restrict__ pc1_0,
    const float* __restrict__ pc2,
    const float* __restrict__ Sp,
    float* __restrict__ out)
{
    int blk = blockIdx.x;            // 1024 blocks
    int batch = blk >> 8;
    int n8 = blk & 255;
    int tid = threadIdx.x;
    float S = Sp[1];
    const float* bb = pc2 + batch * 6144;
    float bx[8], by[8], bz[8];
    {
        const float4* p = (const float4*)(bb + tid * 12);
        float4 u0 = p[0], u1 = p[1], u2 = p[2];
        bx[0]=u0.x; by[0]=u0.y; bz[0]=u0.z;
        bx[1]=u0.w; by[1]=u1.x; bz[1]=u1.y;
        bx[2]=u1.z; by[2]=u1.w; bz[2]=u2.x;
        bx[3]=u2.y; by[3]=u2.z; bz[3]=u2.w;
    }
    {
        const float4* p = (const float4*)(bb + 3072 + tid * 12);
        float4 u0 = p[0], u1 = p[1], u2 = p[2];
        bx[4]=u0.x; by[4]=u0.y; bz[4]=u0.z;
        bx[5]=u0.w; by[5]=u1.x; bz[5]=u1.y;
        bx[6]=u1.z; by[6]=u1.w; bz[6]=u2.x;
        bx[7]=u2.y; by[7]=u2.z; bz[7]=u2.w;
    }
    const float* arow = pc1_0 + batch * 6144 + n8 * 24;  // 8 rows x 3 (uniform)
    float* ob = out + (long)((batch << 11) + (n8 << 3)) * 2048 + tid * 4;
    #pragma unroll
    for (int r = 0; r < 8; r++) {
        float axx = arow[r*3], ayy = arow[r*3+1], azz = arow[r*3+2];
        float o[8];
        #pragma unroll
        for (int k = 0; k < 8; k++) {
            float dx = axx - bx[k], dy = ayy - by[k], dz = azz - bz[k];
            float d2 = fmaf(dx, dx, fmaf(dy, dy, dz*dz));
            o[k] = fmaf(0.5f, sqrtf(d2), S);
        }
        *(float4*)(ob + r * 2048)        = make_float4(o[0], o[1], o[2], o[3]);
        *(float4*)(ob + r * 2048 + 1024) = make_float4(o[4], o[5], o[6], o[7]);
    }
}

extern "C" void kernel_launch(void* const* d_in, const int* in_sizes, int n_in,
                              void* d_out, int out_size, void* d_ws, size_t ws_size,
                              hipStream_t stream) {
    const float* pc1_0 = (const float*)d_in[0];  // [4,2048,3]
    const float* pc1_1 = (const float*)d_in[1];  // [4,1024,3]
    const float* pc1_3 = (const float*)d_in[2];  // [4,2048,1]
    const float* pc2   = (const float*)d_in[3];  // [4,2048,3]
    const float* pc3   = (const float*)d_in[4];  // [4,2048,3]
    float* out = (float*)d_out;
    float* ws  = (float*)d_ws;                   // ws[1] = scalar S accumulator
    float* gmin = out + GMIN_OFS;                // scratch in d_out tail

    init_min<<<145, 256, 0, stream>>>((unsigned int*)gmin, ws);
    nn_kernel<<<832, 256, 0, stream>>>(pc1_0, pc1_1, pc2, pc3, gmin);
    reduce_kernel<<<36, 256, 0, stream>>>(gmin, pc1_3, ws);
    out_kernel<<<1024, 256, 0, stream>>>(pc1_0, pc2, ws, out);
}

// Round 4
// 111.536 us; speedup vs baseline: 1.5137x; 1.0255x over previous
//
#include <hip/hip_runtime.h>
#include <math.h>

// Problem constants (fixed by setup_inputs): B=4, N=M=P=2048, NS=1024.
// out = [4,2048,2048] fp32, out_size = 16777216 floats.
//
// Pipeline (3 kernels):
//  1. nn_kernel<<<832>>>: each block = 1024 a-points x 256 b-points (LDS).
//     Writes 1024 partial clamped-d2 values (min over ITS b-tile) to a
//     3.4 MB partial array in the TAIL of d_out (plain coalesced stores,
//     no init, no atomics). Partial slot for block bid = [bid*1024, +1024).
//  2. reduce_kernel<<<36>>>: per point, min over its b-tile partials
//     (coalesced gather), sqrt / conf-MSE, per-block scaled sum -> ws[blk].
//  3. out_kernel<<<1024>>>: S = sum(ws[0..35]);
//     out[b,n,m] = S + 0.5*dist(pc1_0[b,n], pc2[b,m]). Overwrites the
//     partial tail last; never reads d_out.
//
// Job table (nn, 832 blocks; a_tile = local / b_tiles, b_tile = local % b_tiles):
//   [0,256)    cd:   A=pc1_0(8192) vs B=pc2(8192)    8 at x 32 bt
//   [256,512)  cd:   A=pc2(8192)   vs B=pc1_0(8192)  8 at x 32 bt
//   [512,640)  seed: A=pc1_1(4096) vs B=pc2(8192)    4 at x 32 bt
//   [640,768)  seed: A=pc2(8192)   vs B=pc1_1(4096)  8 at x 16 bt
//   [768,832)  conf: A=pc3[b](2048) vs B=pc2[b](2048) per batch: 2 at x 8 bt

constexpr int OUT_TOTAL  = 4 * 2048 * 2048;
constexpr int PART_TOTAL = 832 * 1024;              // 851968 floats, 3.4 MB
constexpr int PART_OFS   = OUT_TOTAL - PART_TOTAL;

// native vector type for __builtin_nontemporal_store (HIP_vector_type rejected)
typedef float nfloat4 __attribute__((ext_vector_type(4)));

__global__ __launch_bounds__(256) void nn_kernel(
    const float* __restrict__ A0,   // pc1_0 flat (8192 pts)
    const float* __restrict__ A1,   // pc1_1 flat (4096 pts)
    const float* __restrict__ P2,   // pc2   flat (8192 pts / 4 batches x 2048)
    const float* __restrict__ P3,   // pc3   (4 x 2048 pts)
    float* __restrict__ part)
{
    __shared__ float4 lds[256];     // (bx, by, bz, -0.5*|b|^2)
    int bid = blockIdx.x;
    const float* A; const float* Bp; int b_tiles; int local;
    if (bid < 256)      { local = bid;       A = A0; Bp = P2; b_tiles = 32; }
    else if (bid < 512) { local = bid - 256; A = P2; Bp = A0; b_tiles = 32; }
    else if (bid < 640) { local = bid - 512; A = A1; Bp = P2; b_tiles = 32; }
    else if (bid < 768) { local = bid - 640; A = P2; Bp = A1; b_tiles = 16; }
    else { int l2 = bid - 768; int bt = l2 >> 4; local = l2 & 15;
           A = P3 + bt * 6144; Bp = P2 + bt * 6144; b_tiles = 8; }
    int a_tile = local / b_tiles;
    int b_tile = local - a_tile * b_tiles;

    {
        const float* s = Bp + (b_tile * 256 + threadIdx.x) * 3;
        float bx = s[0], by = s[1], bz = s[2];
        float nb2 = -0.5f * fmaf(bx, bx, fmaf(by, by, bz * bz));
        lds[threadIdx.x] = make_float4(bx, by, bz, nb2);
    }

    // 4 a-points per thread (12 consecutive floats, 16B-aligned -> 3x float4)
    int a_base = a_tile * 1024 + threadIdx.x * 4;
    const float4* av = (const float4*)(A + a_base * 3);
    float4 v0 = av[0], v1 = av[1], v2 = av[2];
    float ax[4], ay[4], az[4], a2[4], mx[4];
    ax[0]=v0.x; ay[0]=v0.y; az[0]=v0.z;
    ax[1]=v0.w; ay[1]=v1.x; az[1]=v1.y;
    ax[2]=v1.z; ay[2]=v1.w; az[2]=v2.x;
    ax[3]=v2.y; ay[3]=v2.z; az[3]=v2.w;
    #pragma unroll
    for (int k = 0; k < 4; k++) {
        a2[k] = fmaf(ax[k], ax[k], fmaf(ay[k], ay[k], az[k]*az[k]));
        mx[k] = -3.4e38f;
    }
    __syncthreads();

    // maximize (a.b - 0.5|b|^2); d2 = max(|a|^2 - 2*mx, 0). 4 VALU ops/pair.
    #pragma unroll 4
    for (int j = 0; j < 256; j++) {
        float4 b = lds[j];
        #pragma unroll
        for (int k = 0; k < 4; k++) {
            float u = fmaf(az[k], b.z, b.w);
            u = fmaf(ay[k], b.y, u);
            u = fmaf(ax[k], b.x, u);
            mx[k] = fmaxf(mx[k], u);
        }
    }
    float4 o;
    o.x = fmaxf(fmaf(-2.f, mx[0], a2[0]), 0.f);
    o.y = fmaxf(fmaf(-2.f, mx[1], a2[1]), 0.f);
    o.z = fmaxf(fmaf(-2.f, mx[2], a2[2]), 0.f);
    o.w = fmaxf(fmaf(-2.f, mx[3], a2[3]), 0.f);
    *(float4*)(part + bid * 1024 + threadIdx.x * 4) = o;
}

// 36 blocks x 1024 points. Block -> (partial-base block pb, tile count bt):
//   blk<8:  pb=blk*32          bt=32   (cd dir2, /8192 * 0.5)
//   <16:    pb=256+(blk-8)*32  bt=32   (cd dir1, /8192 * 0.5)
//   <20:    pb=512+(blk-16)*32 bt=32   (seed dir2, /4096)
//   <28:    pb=640+(blk-20)*16 bt=16   (seed dir1, /8192)
//   <36:    pb=768+(blk-28)*8  bt=8    (conf, MSE /8192)
__global__ __launch_bounds__(256) void reduce_kernel(
    const float* __restrict__ part,
    const float* __restrict__ conf_in,   // pc1_3, 8192 values
    float* __restrict__ ws)
{
    int blk = blockIdx.x;
    int tid = threadIdx.x;
    int pb, bt;
    if (blk < 8)       { pb = blk * 32;              bt = 32; }
    else if (blk < 16) { pb = 256 + (blk - 8) * 32;  bt = 32; }
    else if (blk < 20) { pb = 512 + (blk - 16) * 32; bt = 32; }
    else if (blk < 28) { pb = 640 + (blk - 20) * 16; bt = 16; }
    else               { pb = 768 + (blk - 28) * 8;  bt = 8;  }

    float m0 = 3.4e38f, m1 = 3.4e38f, m2 = 3.4e38f, m3 = 3.4e38f;
    const float* p = part + (pb << 10) + tid;
    #pragma unroll 4
    for (int t = 0; t < bt; t++, p += 1024) {
        m0 = fminf(m0, p[0]);
        m1 = fminf(m1, p[256]);
        m2 = fminf(m2, p[512]);
        m3 = fminf(m3, p[768]);
    }
    float d0 = sqrtf(m0), d1 = sqrtf(m1), d2 = sqrtf(m2), d3 = sqrtf(m3);
    float sum;
    if (blk < 28) {
        sum = (d0 + d1) + (d2 + d3);
    } else {
        const float* c = conf_in + (blk - 28) * 1024 + tid;
        float e0 = c[0]   - __expf(-d0);
        float e1 = c[256] - __expf(-d1);
        float e2 = c[512] - __expf(-d2);
        float e3 = c[768] - __expf(-d3);
        sum = fmaf(e0, e0, e1 * e1) + fmaf(e2, e2, e3 * e3);
    }
    #pragma unroll
    for (int ofs = 32; ofs > 0; ofs >>= 1) sum += __shfl_down(sum, ofs);
    __shared__ float red[4];
    if ((tid & 63) == 0) red[tid >> 6] = sum;
    __syncthreads();
    if (tid == 0) {
        float tot = (red[0] + red[1]) + (red[2] + red[3]);
        float scale = (blk < 16) ? 0.5f / 8192.f
                    : (blk < 20) ? 1.f / 4096.f
                    :              1.f / 8192.f;
        ws[blk] = tot * scale;
    }
}

// out[b,n,m] = S + 0.5 * dist(pc1_0[b,n], pc2[b,m]).
// Block = (batch, group of 8 n-rows). Thread owns m = tid*4..+3 and
// 1024+tid*4..+3 (8 pc2 points in registers); nontemporal float4 stores.
__global__ __launch_bounds__(256) void out_kernel(
    const float* __restrict__ pc1_0,
    const float* __restrict__ pc2,
    const float* __restrict__ wsp,
    float* __restrict__ out)
{
    int blk = blockIdx.x;            // 1024 blocks
    int batch = blk >> 8;
    int n8 = blk & 255;
    int tid = threadIdx.x;
    float S = 0.f;
    #pragma unroll
    for (int t = 0; t < 36; t++) S += wsp[t];   // uniform -> s_loads
    const float* bb = pc2 + batch * 6144;
    float bx[8], by[8], bz[8];
    {
        const float4* p = (const float4*)(bb + tid * 12);
        float4 u0 = p[0], u1 = p[1], u2 = p[2];
        bx[0]=u0.x; by[0]=u0.y; bz[0]=u0.z;
        bx[1]=u0.w; by[1]=u1.x; bz[1]=u1.y;
        bx[2]=u1.z; by[2]=u1.w; bz[2]=u2.x;
        bx[3]=u2.y; by[3]=u2.z; bz[3]=u2.w;
    }
    {
        const float4* p = (const float4*)(bb + 3072 + tid * 12);
        float4 u0 = p[0], u1 = p[1], u2 = p[2];
        bx[4]=u0.x; by[4]=u0.y; bz[4]=u0.z;
        bx[5]=u0.w; by[5]=u1.x; bz[5]=u1.y;
        bx[6]=u1.z; by[6]=u1.w; bz[6]=u2.x;
        bx[7]=u2.y; by[7]=u2.z; bz[7]=u2.w;
    }
    const float* arow = pc1_0 + batch * 6144 + n8 * 24;  // 8 rows x 3 (uniform)
    float* ob = out + (long)((batch << 11) + (n8 << 3)) * 2048 + tid * 4;
    #pragma unroll
    for (int r = 0; r < 8; r++) {
        float axx = arow[r*3], ayy = arow[r*3+1], azz = arow[r*3+2];
        float o[8];
        #pragma unroll
        for (int k = 0; k < 8; k++) {
            float dx = axx - bx[k], dy = ayy - by[k], dz = azz - bz[k];
            float d2 = fmaf(dx, dx, fmaf(dy, dy, dz*dz));
            o[k] = fmaf(0.5f, sqrtf(d2), S);
        }
        nfloat4 lo = { o[0], o[1], o[2], o[3] };
        nfloat4 hi = { o[4], o[5], o[6], o[7] };
        __builtin_nontemporal_store(lo, (nfloat4*)(ob + r * 2048));
        __builtin_nontemporal_store(hi, (nfloat4*)(ob + r * 2048 + 1024));
    }
}

extern "C" void kernel_launch(void* const* d_in, const int* in_sizes, int n_in,
                              void* d_out, int out_size, void* d_ws, size_t ws_size,
                              hipStream_t stream) {
    const float* pc1_0 = (const float*)d_in[0];  // [4,2048,3]
    const float* pc1_1 = (const float*)d_in[1];  // [4,1024,3]
    const float* pc1_3 = (const float*)d_in[2];  // [4,2048,1]
    const float* pc2   = (const float*)d_in[3];  // [4,2048,3]
    const float* pc3   = (const float*)d_in[4];  // [4,2048,3]
    float* out = (float*)d_out;
    float* ws  = (float*)d_ws;                   // ws[0..35]: scaled partial sums
    float* part = out + PART_OFS;                // partial-min scratch in d_out tail

    nn_kernel<<<832, 256, 0, stream>>>(pc1_0, pc1_1, pc2, pc3, part);
    reduce_kernel<<<36, 256, 0, stream>>>(part, pc1_3, ws);
    out_kernel<<<1024, 256, 0, stream>>>(pc1_0, pc2, ws, out);
}